// Round 2
// baseline (3989.371 us; speedup 1.0000x reference)
//
#include <hip/hip_runtime.h>
#include <cstdint>
#include <cstddef>

// ---------------------------------------------------------------------------
// MultiLayer bidirectional TreeLSTM, N=4096 balanced heap tree, H=512, L=2.
// Strategy: level-parallel scan. Level k = nodes [2^k-1, 2^(k+1)-2].
// Leaves (nodes 2048..4095) have no children -> no GEMM needed (children are
// the zero slot). fwd stage GEMM fuses left+right child matmuls into one
// K=1024 GEMM with gathered A rows. h buffers have a 4097th row of zeros
// (slot for missing child / root parent), matching the reference's row n.
// Workspace (~126 MB): A1,A2 [4097x1024] (per-layer concat h, ping-pong),
// px [4096x512], x2 [4096x3072], cb [4097x512], G [2048x3072].
// ---------------------------------------------------------------------------

#define N_OBJ 4096
#define IN_DIM 1024
#define HDIM 512
#define ZROW N_OBJ   // zero slot row index (4096)

#define BM 64
#define BN 64
#define BK 16
#define LSTR 68      // LDS leading stride (floats): 16B-aligned rows, conflict-lite

__device__ __forceinline__ float sigm(float x) { return 1.0f / (1.0f + expf(-x)); }

// ---------------------------------------------------------------------------
// C[M,N] = A[M,K] @ W[N,K]^T + bias[N]
// A row-major stride K, W row-major stride K. M=4096, N,K multiples of 64/16.
// ---------------------------------------------------------------------------
__global__ __launch_bounds__(256) void gemm_xw(
    const float* __restrict__ A, const float* __restrict__ W,
    const float* __restrict__ bias, float* __restrict__ C,
    int N, int K)
{
    __shared__ __align__(16) float As[BK * LSTR];
    __shared__ __align__(16) float Bs[BK * LSTR];
    const int tid  = threadIdx.x;
    const int lrow = tid >> 2;        // 0..63
    const int lk4  = (tid & 3) << 2;  // 0,4,8,12
    const int r0   = (tid >> 4) << 2; // 0..60
    const int c0   = (tid & 15) << 2; // 0..60

    const float* Ap = A + (size_t)(blockIdx.y * BM + lrow) * K + lk4;
    const float* Wp = W + (size_t)(blockIdx.x * BN + lrow) * K + lk4;

    float acc[4][4] = {};
    for (int kt = 0; kt < K; kt += BK) {
        float4 av = *(const float4*)(Ap + kt);
        float4 wv = *(const float4*)(Wp + kt);
        __syncthreads();
        As[(lk4 + 0) * LSTR + lrow] = av.x;
        As[(lk4 + 1) * LSTR + lrow] = av.y;
        As[(lk4 + 2) * LSTR + lrow] = av.z;
        As[(lk4 + 3) * LSTR + lrow] = av.w;
        Bs[(lk4 + 0) * LSTR + lrow] = wv.x;
        Bs[(lk4 + 1) * LSTR + lrow] = wv.y;
        Bs[(lk4 + 2) * LSTR + lrow] = wv.z;
        Bs[(lk4 + 3) * LSTR + lrow] = wv.w;
        __syncthreads();
#pragma unroll
        for (int k = 0; k < BK; ++k) {
            float4 a = *(const float4*)(As + k * LSTR + r0);
            float4 b = *(const float4*)(Bs + k * LSTR + c0);
            float aa[4] = {a.x, a.y, a.z, a.w};
            float bb[4] = {b.x, b.y, b.z, b.w};
#pragma unroll
            for (int i = 0; i < 4; ++i)
#pragma unroll
                for (int j = 0; j < 4; ++j)
                    acc[i][j] = fmaf(aa[i], bb[j], acc[i][j]);
        }
    }
    const int gr = blockIdx.y * BM + r0;
    const int gc = blockIdx.x * BN + c0;
    float4 bv = *(const float4*)(bias + gc);
#pragma unroll
    for (int i = 0; i < 4; ++i) {
        float4 o;
        o.x = acc[i][0] + bv.x; o.y = acc[i][1] + bv.y;
        o.z = acc[i][2] + bv.z; o.w = acc[i][3] + bv.w;
        *(float4*)(C + (size_t)(gr + i) * N + gc) = o;
    }
}

// ---------------------------------------------------------------------------
// fwd stage: G[r, 0:3072] = x2[base+r] + h[lc]@Wl^T + h[rc]@Wr^T
// (bl, br added in elementwise). Gathered-A GEMM, K=1024 (left half -> lc/Wl,
// right half -> rc/Wr). Hbuf = concat-h buffer [4097,1024], fwd h at cols 0..511.
// ---------------------------------------------------------------------------
__global__ __launch_bounds__(256) void stage_gemm_fwd(
    const float* __restrict__ Hbuf,
    const int* __restrict__ lc, const int* __restrict__ rc,
    int base, int m,
    const float* __restrict__ Wl, const float* __restrict__ Wr,
    const float* __restrict__ x2, float* __restrict__ G)
{
    __shared__ __align__(16) float As[BK * LSTR];
    __shared__ __align__(16) float Bs[BK * LSTR];
    const int tid  = threadIdx.x;
    const int lrow = tid >> 2;
    const int lk4  = (tid & 3) << 2;
    const int r0   = (tid >> 4) << 2;
    const int c0   = (tid & 15) << 2;

    const int arow = blockIdx.y * BM + lrow;
    int lcn = ZROW, rcn = ZROW;
    if (arow < m) { lcn = lc[base + arow]; rcn = rc[base + arow]; }
    const float* hl = Hbuf + (size_t)lcn * 1024 + lk4;   // zeros if slot 4096
    const float* hr = Hbuf + (size_t)rcn * 1024 + lk4;
    const int nrow = blockIdx.x * BN + lrow;
    const float* wl = Wl + (size_t)nrow * HDIM + lk4;
    const float* wr = Wr + (size_t)nrow * HDIM + lk4;

    float acc[4][4] = {};
#pragma unroll 1
    for (int half = 0; half < 2; ++half) {
        const float* hsrc = half ? hr : hl;
        const float* wsrc = half ? wr : wl;
        for (int kt = 0; kt < HDIM; kt += BK) {
            float4 av = *(const float4*)(hsrc + kt);
            float4 wv = *(const float4*)(wsrc + kt);
            __syncthreads();
            As[(lk4 + 0) * LSTR + lrow] = av.x;
            As[(lk4 + 1) * LSTR + lrow] = av.y;
            As[(lk4 + 2) * LSTR + lrow] = av.z;
            As[(lk4 + 3) * LSTR + lrow] = av.w;
            Bs[(lk4 + 0) * LSTR + lrow] = wv.x;
            Bs[(lk4 + 1) * LSTR + lrow] = wv.y;
            Bs[(lk4 + 2) * LSTR + lrow] = wv.z;
            Bs[(lk4 + 3) * LSTR + lrow] = wv.w;
            __syncthreads();
#pragma unroll
            for (int k = 0; k < BK; ++k) {
                float4 a = *(const float4*)(As + k * LSTR + r0);
                float4 b = *(const float4*)(Bs + k * LSTR + c0);
                float aa[4] = {a.x, a.y, a.z, a.w};
                float bb[4] = {b.x, b.y, b.z, b.w};
#pragma unroll
                for (int i = 0; i < 4; ++i)
#pragma unroll
                    for (int j = 0; j < 4; ++j)
                        acc[i][j] = fmaf(aa[i], bb[j], acc[i][j]);
            }
        }
    }
    const int gr = blockIdx.y * BM + r0;
    const int gc = blockIdx.x * BN + c0;
#pragma unroll
    for (int i = 0; i < 4; ++i) {
        if (gr + i < m) {
            float4 xv = *(const float4*)(x2 + (size_t)(base + gr + i) * 3072 + gc);
            float4 o;
            o.x = acc[i][0] + xv.x; o.y = acc[i][1] + xv.y;
            o.z = acc[i][2] + xv.z; o.w = acc[i][3] + xv.w;
            *(float4*)(G + (size_t)(gr + i) * 3072 + gc) = o;
        }
    }
}

// ---------------------------------------------------------------------------
// bwd stage: G[r, 0:2560] = x2[base+r] + h[parent]@Wh^T  (bh added later).
// K=512, bwd h stored at Hbuf cols 512..1023.
// ---------------------------------------------------------------------------
__global__ __launch_bounds__(256) void stage_gemm_bwd(
    const float* __restrict__ Hbuf,
    const int* __restrict__ par,
    int base, int m,
    const float* __restrict__ Wh,
    const float* __restrict__ x2, float* __restrict__ G)
{
    __shared__ __align__(16) float As[BK * LSTR];
    __shared__ __align__(16) float Bs[BK * LSTR];
    const int tid  = threadIdx.x;
    const int lrow = tid >> 2;
    const int lk4  = (tid & 3) << 2;
    const int r0   = (tid >> 4) << 2;
    const int c0   = (tid & 15) << 2;

    const int arow = blockIdx.y * BM + lrow;
    int p = ZROW;
    if (arow < m) p = par[base + arow];
    const float* hp = Hbuf + (size_t)p * 1024 + HDIM + lk4;  // bwd h at col 512
    const int nrow = blockIdx.x * BN + lrow;
    const float* wh = Wh + (size_t)nrow * HDIM + lk4;

    float acc[4][4] = {};
    for (int kt = 0; kt < HDIM; kt += BK) {
        float4 av = *(const float4*)(hp + kt);
        float4 wv = *(const float4*)(wh + kt);
        __syncthreads();
        As[(lk4 + 0) * LSTR + lrow] = av.x;
        As[(lk4 + 1) * LSTR + lrow] = av.y;
        As[(lk4 + 2) * LSTR + lrow] = av.z;
        As[(lk4 + 3) * LSTR + lrow] = av.w;
        Bs[(lk4 + 0) * LSTR + lrow] = wv.x;
        Bs[(lk4 + 1) * LSTR + lrow] = wv.y;
        Bs[(lk4 + 2) * LSTR + lrow] = wv.z;
        Bs[(lk4 + 3) * LSTR + lrow] = wv.w;
        __syncthreads();
#pragma unroll
        for (int k = 0; k < BK; ++k) {
            float4 a = *(const float4*)(As + k * LSTR + r0);
            float4 b = *(const float4*)(Bs + k * LSTR + c0);
            float aa[4] = {a.x, a.y, a.z, a.w};
            float bb[4] = {b.x, b.y, b.z, b.w};
#pragma unroll
            for (int i = 0; i < 4; ++i)
#pragma unroll
                for (int j = 0; j < 4; ++j)
                    acc[i][j] = fmaf(aa[i], bb[j], acc[i][j]);
        }
    }
    const int gr = blockIdx.y * BM + r0;
    const int gc = blockIdx.x * BN + c0;
#pragma unroll
    for (int i = 0; i < 4; ++i) {
        if (gr + i < m) {
            float4 xv = *(const float4*)(x2 + (size_t)(base + gr + i) * 2560 + gc);
            float4 o;
            o.x = acc[i][0] + xv.x; o.y = acc[i][1] + xv.y;
            o.z = acc[i][2] + xv.z; o.w = acc[i][3] + xv.w;
            *(float4*)(G + (size_t)(gr + i) * 2560 + gc) = o;
        }
    }
}

// ---------------------------------------------------------------------------
// fwd elementwise: gates -> c, h. g row = G[row] (rowIsNode=0) or x2[node]
// (rowIsNode=1, leaf batch: children are zero slot so GEMM term vanishes).
// ---------------------------------------------------------------------------
__global__ __launch_bounds__(256) void elem_fwd(
    const float* __restrict__ g, int rowIsNode,
    int base, int m, const int* __restrict__ lc, const int* __restrict__ rc,
    float* __restrict__ cbuf, const float* __restrict__ px,
    float* __restrict__ Aout, const float* __restrict__ bl,
    const float* __restrict__ br)
{
    int t = blockIdx.x * 256 + threadIdx.x;
    if (t >= m * HDIM) return;
    int row = t >> 9, j = t & (HDIM - 1);
    int node = base + row;
    const float* gp = g + (size_t)(rowIsNode ? node : row) * 3072;
    float gi  = gp[j]            + bl[j]            + br[j];
    float go  = gp[HDIM + j]     + bl[HDIM + j]     + br[HDIM + j];
    float gfl = gp[2 * HDIM + j] + bl[2 * HDIM + j] + br[2 * HDIM + j];
    float gfr = gp[3 * HDIM + j] + bl[3 * HDIM + j] + br[3 * HDIM + j];
    float gu  = gp[4 * HDIM + j] + bl[4 * HDIM + j] + br[4 * HDIM + j];
    float grr = gp[5 * HDIM + j] + bl[5 * HDIM + j] + br[5 * HDIM + j];
    int lcn = lc[node], rcn = rc[node];
    float clv = cbuf[(size_t)lcn * HDIM + j];
    float crv = cbuf[(size_t)rcn * HDIM + j];
    float i_ = sigm(gi), o_ = sigm(go), fl_ = sigm(gfl), fr_ = sigm(gfr);
    float u_ = tanhf(gu), r_ = sigm(grr);
    float c  = i_ * u_ + fl_ * clv + fr_ * crv;
    float hc = o_ * tanhf(c);
    float hf = r_ * hc + (1.0f - r_) * px[(size_t)node * HDIM + j];
    cbuf[(size_t)node * HDIM + j] = c;
    Aout[(size_t)node * 1024 + j] = hf;
}

__global__ __launch_bounds__(256) void elem_bwd(
    const float* __restrict__ G,
    int base, int m, const int* __restrict__ par,
    float* __restrict__ cbuf, const float* __restrict__ px,
    float* __restrict__ Aout, const float* __restrict__ bh)
{
    int t = blockIdx.x * 256 + threadIdx.x;
    if (t >= m * HDIM) return;
    int row = t >> 9, j = t & (HDIM - 1);
    int node = base + row;
    const float* gp = G + (size_t)row * 2560;
    float gi = gp[j]            + bh[j];
    float go = gp[HDIM + j]     + bh[HDIM + j];
    float gf = gp[2 * HDIM + j] + bh[2 * HDIM + j];
    float gu = gp[3 * HDIM + j] + bh[3 * HDIM + j];
    float gr = gp[4 * HDIM + j] + bh[4 * HDIM + j];
    int p = par[node];
    float cp = cbuf[(size_t)p * HDIM + j];
    float i_ = sigm(gi), o_ = sigm(go), f_ = sigm(gf);
    float u_ = tanhf(gu), r_ = sigm(gr);
    float c  = i_ * u_ + f_ * cp;
    float hc = o_ * tanhf(c);
    float hf = r_ * hc + (1.0f - r_) * px[(size_t)node * HDIM + j];
    cbuf[(size_t)node * HDIM + j] = c;
    Aout[(size_t)node * 1024 + HDIM + j] = hf;
}

// zero the "missing child / root parent" slot rows (d_ws is poisoned each call)
__global__ void zero_slots(float* A1, float* A2, float* cb)
{
    int t = threadIdx.x;  // 1024 threads
    A1[(size_t)ZROW * 1024 + t] = 0.0f;
    A2[(size_t)ZROW * 1024 + t] = 0.0f;
    if (t < HDIM) cb[(size_t)ZROW * HDIM + t] = 0.0f;
}

extern "C" void kernel_launch(void* const* d_in, const int* in_sizes, int n_in,
                              void* d_out, int out_size, void* d_ws, size_t ws_size,
                              hipStream_t stream)
{
    (void)in_sizes; (void)n_in; (void)out_size; (void)ws_size;
    const float* features = (const float*)d_in[0];
    const float* fw_Wp = (const float*)d_in[1];
    const float* fw_bp = (const float*)d_in[2];
    const float* fw_Wx = (const float*)d_in[3];
    const float* fw_bx = (const float*)d_in[4];
    const float* fw_Wl = (const float*)d_in[5];
    const float* fw_bl = (const float*)d_in[6];
    const float* fw_Wr = (const float*)d_in[7];
    const float* fw_br = (const float*)d_in[8];
    const float* bw_Wp = (const float*)d_in[9];
    const float* bw_bp = (const float*)d_in[10];
    const float* bw_Wx = (const float*)d_in[11];
    const float* bw_bx = (const float*)d_in[12];
    const float* bw_Wh = (const float*)d_in[13];
    const float* bw_bh = (const float*)d_in[14];
    const int* lc  = (const int*)d_in[17];
    const int* rc  = (const int*)d_in[18];
    const int* par = (const int*)d_in[19];

    float* A1 = (float*)d_ws;
    float* A2 = A1 + (size_t)(N_OBJ + 1) * 1024;
    float* px = A2 + (size_t)(N_OBJ + 1) * 1024;
    float* x2 = px + (size_t)N_OBJ * HDIM;
    float* cb = x2 + (size_t)N_OBJ * 3072;
    float* G  = cb + (size_t)(N_OBJ + 1) * HDIM;
    // total: ~31.5M floats (~126 MB)

    zero_slots<<<dim3(1), dim3(1024), 0, stream>>>(A1, A2, cb);

    for (int l = 0; l < 2; ++l) {
        const float* fin = (l == 0) ? features : A1;
        float* fout = (l == 0) ? A1 : A2;

        // ---------------- forward (leaves -> root) ----------------
        gemm_xw<<<dim3(HDIM / BN, N_OBJ / BM), 256, 0, stream>>>(
            fin, fw_Wp + (size_t)l * HDIM * IN_DIM, fw_bp + (size_t)l * HDIM,
            px, HDIM, IN_DIM);
        gemm_xw<<<dim3(3072 / BN, N_OBJ / BM), 256, 0, stream>>>(
            fin, fw_Wx + (size_t)l * 3072 * IN_DIM, fw_bx + (size_t)l * 3072,
            x2, 3072, IN_DIM);
        const float* Wl_l = fw_Wl + (size_t)l * 3072 * HDIM;
        const float* Wr_l = fw_Wr + (size_t)l * 3072 * HDIM;
        const float* bl_l = fw_bl + (size_t)l * 3072;
        const float* br_l = fw_br + (size_t)l * 3072;

        // leaves 2048..4095: children are zero-slot -> g = x2 row, no GEMM
        {
            int tot = 2048 * HDIM;
            elem_fwd<<<dim3((tot + 255) / 256), 256, 0, stream>>>(
                x2, 1, 2048, 2048, lc, rc, cb, px, fout, bl_l, br_l);
        }
        auto stageF = [&](int base, int m) {
            stage_gemm_fwd<<<dim3(3072 / BN, (m + BM - 1) / BM), 256, 0, stream>>>(
                fout, lc, rc, base, m, Wl_l, Wr_l, x2, G);
            int tot = m * HDIM;
            elem_fwd<<<dim3((tot + 255) / 256), 256, 0, stream>>>(
                G, 0, base, m, lc, rc, cb, px, fout, bl_l, br_l);
        };
        stageF(2047, 1);                                   // needs leaf 4095
        for (int k = 10; k >= 0; --k) stageF((1 << k) - 1, 1 << k);

        // ---------------- backward (root -> leaves) ----------------
        gemm_xw<<<dim3(HDIM / BN, N_OBJ / BM), 256, 0, stream>>>(
            fin, bw_Wp + (size_t)l * HDIM * IN_DIM, bw_bp + (size_t)l * HDIM,
            px, HDIM, IN_DIM);
        gemm_xw<<<dim3(2560 / BN, N_OBJ / BM), 256, 0, stream>>>(
            fin, bw_Wx + (size_t)l * 2560 * IN_DIM, bw_bx + (size_t)l * 2560,
            x2, 2560, IN_DIM);
        const float* Wh_l = bw_Wh + (size_t)l * 2560 * HDIM;
        const float* bh_l = bw_bh + (size_t)l * 2560;

        for (int k = 0; k <= 12; ++k) {
            int base = (1 << k) - 1;
            int m = 1 << k;
            if (base + m > N_OBJ) m = N_OBJ - base;
            stage_gemm_bwd<<<dim3(2560 / BN, (m + BM - 1) / BM), 256, 0, stream>>>(
                fout, par, base, m, Wh_l, x2, G);
            int tot = m * HDIM;
            elem_bwd<<<dim3((tot + 255) / 256), 256, 0, stream>>>(
                G, base, m, par, cb, px, fout, bh_l);
        }
    }

    hipMemcpyAsync(d_out, A2, (size_t)N_OBJ * 1024 * sizeof(float),
                   hipMemcpyDeviceToDevice, stream);
}

// Round 5
// 1857.758 us; speedup vs baseline: 2.1474x; 2.1474x over previous
//
#include <hip/hip_runtime.h>
#include <cstdint>
#include <cstddef>

// ---------------------------------------------------------------------------
// MultiLayer bidirectional TreeLSTM, N=4096 heap tree, H=512, L=2.
// R5: f16 MFMA (fp32 acc) for all GEMMs + THE GATHER FIX:
//   R3/R4 bug: MODE 1/2 gathered idx[base + srow] where srow = row-in-tile
//   (0..127); must be idx[base + blockIdx.y*128 + srow]. All stages with
//   m > 128 read wrong children/parents -> dtype-independent absmax ~1.53.
// f16 chosen over bf16: 2^-11 operand rounding -> predicted absmax ~0.01
// vs 0.044 threshold. Single vector type (f16x8) for all GEMM data movement.
// Cell state c, gates, highway mix, d_out: fp32. h / PX / G stored f16.
// Workspace ~112 MB (R2 proved >=126 MB available).
// ---------------------------------------------------------------------------

#define HDIM 512
#define ZROW 4096
#define NCAT 6656   // 512 px_f | 3072 x2_f | 512 px_b | 2560 x2_b

typedef _Float16 f16;
typedef f16   f16x8 __attribute__((ext_vector_type(8)));
typedef float f32x4 __attribute__((ext_vector_type(4)));

__device__ __forceinline__ float sigm(float x) { return 1.0f / (1.0f + expf(-x)); }

// ---------------------------------------------------------------------------
// fp32 -> fp16 convert, 8 elements/thread
// ---------------------------------------------------------------------------
__global__ __launch_bounds__(256) void cvt16(
    const float* __restrict__ s, f16* __restrict__ d, int n8)
{
    int i = blockIdx.x * 256 + threadIdx.x;
    if (i >= n8) return;
    float4 v0 = ((const float4*)s)[(size_t)i * 2];
    float4 v1 = ((const float4*)s)[(size_t)i * 2 + 1];
    f16x8 o;
    o[0] = (f16)v0.x; o[1] = (f16)v0.y; o[2] = (f16)v0.z; o[3] = (f16)v0.w;
    o[4] = (f16)v1.x; o[5] = (f16)v1.y; o[6] = (f16)v1.z; o[7] = (f16)v1.w;
    *(f16x8*)(d + (size_t)i * 8) = o;
}

// concat Wl|Wr along K: dst[3072][1024] f16
__global__ __launch_bounds__(256) void cvt16_lr(
    const float* __restrict__ Wl, const float* __restrict__ Wr, f16* __restrict__ d)
{
    int i = blockIdx.x * 256 + threadIdx.x;   // over 3072*1024/8
    int col8 = (i * 8) & 1023;
    int row  = (i * 8) >> 10;
    const float* s = (col8 < HDIM) ? (Wl + (size_t)row * HDIM + col8)
                                   : (Wr + (size_t)row * HDIM + col8 - HDIM);
    float4 v0 = ((const float4*)s)[0];
    float4 v1 = ((const float4*)s)[1];
    f16x8 o;
    o[0] = (f16)v0.x; o[1] = (f16)v0.y; o[2] = (f16)v0.z; o[3] = (f16)v0.w;
    o[4] = (f16)v1.x; o[5] = (f16)v1.y; o[6] = (f16)v1.z; o[7] = (f16)v1.w;
    *(f16x8*)(d + (size_t)i * 8) = o;
}

__global__ __launch_bounds__(256) void biascat_k(
    const float* __restrict__ a, const float* __restrict__ b,
    const float* __restrict__ c, const float* __restrict__ dd,
    float* __restrict__ o)
{
    int t = blockIdx.x * 256 + threadIdx.x;
    if (t >= NCAT) return;
    float v;
    if (t < 512) v = a[t];
    else if (t < 3584) v = b[t - 512];
    else if (t < 4096) v = c[t - 3584];
    else v = dd[t - 4096];
    o[t] = v;
}

__global__ void zero_slots(f16* H, float* cb)
{
    int t = threadIdx.x;  // 1024 threads
    H[(size_t)ZROW * 1024 + t] = (f16)0.0f;
    if (t < HDIM) cb[(size_t)ZROW * HDIM + t] = 0.0f;
}

// ---------------------------------------------------------------------------
// MFMA GEMM: C[M,N] = A[M,K] @ W[N,K]^T (+bias), f16 in, f32 acc, f16 out.
// 128x128 tile, 4 waves (2x2), each wave 4x4 MFMA 16x16x32 tiles.
// MODE 0: A rows direct, +bias.  MODE 1: fwd gather (lc/rc, K=1024,
// A[r][k] = H[k<512?lc:rc][k&511]).  MODE 2: bwd gather (par, K=512,
// A[r][k] = H[par][512+k]).  Gather index = base + GLOBAL row (bugfix R5).
// Rows >= m gather the zero row; epilogue guarded.
// LDS row stride 40 f16 (80 B): 2-way bank aliasing only (free, m136).
// ---------------------------------------------------------------------------
template<int MODE>
__global__ __launch_bounds__(256) void mm16(
    const f16* __restrict__ A, const int* __restrict__ idx1,
    const int* __restrict__ idx2, int base, int m,
    const f16* __restrict__ W, const float* __restrict__ bias,
    f16* __restrict__ C, int N, int K)
{
    __shared__ __align__(16) f16 Al[128 * 40];
    __shared__ __align__(16) f16 Bl[128 * 40];
    const int t  = threadIdx.x;
    const int L  = t & 63;
    const int w  = t >> 6;
    const int wm = (w & 1) << 6;
    const int wn = (w >> 1) << 6;
    const int srow = t & 127;
    const int sch  = t >> 7;          // 0/1: which 16-f16 chunk of the 32-K tile
    const int fr = L & 15;
    const int fq = L >> 4;

    const int grow = blockIdx.y * 128 + srow;   // GLOBAL A-row (the R5 fix)
    const f16* ap0;
    const f16* ap1 = nullptr;
    if (MODE == 0) {
        ap0 = A + (size_t)grow * K;
    } else if (MODE == 1) {
        int n1 = ZROW, n2 = ZROW;
        if (grow < m) { n1 = idx1[base + grow]; n2 = idx2[base + grow]; }
        ap0 = A + (size_t)n1 * 1024;
        ap1 = A + (size_t)n2 * 1024;
    } else {
        int n1 = ZROW;
        if (grow < m) n1 = idx1[base + grow];
        ap0 = A + (size_t)n1 * 1024 + HDIM;
    }
    const f16* bp = W + (size_t)(blockIdx.x * 128 + srow) * K;

    f32x4 acc[4][4] = {};

    for (int k0 = 0; k0 < K; k0 += 32) {
        const int kc = k0 + sch * 16;
        const f16* asrc;
        if (MODE == 1) asrc = (kc < HDIM) ? (ap0 + kc) : (ap1 + (kc - HDIM));
        else           asrc = ap0 + kc;
        f16x8 a0 = *(const f16x8*)asrc;
        f16x8 a1 = *(const f16x8*)(asrc + 8);
        f16x8 b0 = *(const f16x8*)(bp + kc);
        f16x8 b1 = *(const f16x8*)(bp + kc + 8);
        __syncthreads();
        f16* ad = Al + srow * 40 + sch * 16;
        *(f16x8*)ad = a0; *(f16x8*)(ad + 8) = a1;
        f16* bd = Bl + srow * 40 + sch * 16;
        *(f16x8*)bd = b0; *(f16x8*)(bd + 8) = b1;
        __syncthreads();
        f16x8 af[4], bg[4];
#pragma unroll
        for (int i = 0; i < 4; ++i)
            af[i] = *(const f16x8*)(Al + (wm + i * 16 + fr) * 40 + fq * 8);
#pragma unroll
        for (int j = 0; j < 4; ++j)
            bg[j] = *(const f16x8*)(Bl + (wn + j * 16 + fr) * 40 + fq * 8);
#pragma unroll
        for (int i = 0; i < 4; ++i)
#pragma unroll
            for (int j = 0; j < 4; ++j)
                acc[i][j] = __builtin_amdgcn_mfma_f32_16x16x32_f16(
                    af[i], bg[j], acc[i][j], 0, 0, 0);
    }

    // C/D layout: col = lane&15, row = (lane>>4)*4 + reg  [m89-verified,
    // dtype-independent per m121-m128]
    const int gr0 = blockIdx.y * 128 + wm + fq * 4;
    const int gc0 = blockIdx.x * 128 + wn + fr;
#pragma unroll
    for (int j = 0; j < 4; ++j) {
        const int gc = gc0 + j * 16;
        const float bj = (MODE == 0) ? bias[gc] : 0.0f;
#pragma unroll
        for (int i = 0; i < 4; ++i) {
            const int gr = gr0 + i * 16;
#pragma unroll
            for (int rr = 0; rr < 4; ++rr) {
                if (MODE == 0 || gr + rr < m)
                    C[(size_t)(gr + rr) * N + gc] = (f16)(acc[i][j][rr] + bj);
            }
        }
    }
}

// ---------------------------------------------------------------------------
// fwd elementwise: g = G(row) [stage matmul, null for leaves] + x2_f + bl + br
// ---------------------------------------------------------------------------
__global__ __launch_bounds__(256) void elem_fwd(
    const f16* __restrict__ G, int gstride,
    const f16* __restrict__ PX,
    int base, int m, const int* __restrict__ lc, const int* __restrict__ rc,
    float* __restrict__ cb, f16* __restrict__ H, float* __restrict__ out32,
    const float* __restrict__ bl, const float* __restrict__ br)
{
    int t = blockIdx.x * 256 + threadIdx.x;
    if (t >= m * HDIM) return;
    int row = t >> 9, j = t & (HDIM - 1);
    int node = base + row;
    const f16* pxr = PX + (size_t)node * NCAT;
    float g[6];
#pragma unroll
    for (int q = 0; q < 6; ++q) {
        float v = (float)pxr[HDIM + q * HDIM + j] + bl[q * HDIM + j] + br[q * HDIM + j];
        if (G) v += (float)G[(size_t)row * gstride + q * HDIM + j];
        g[q] = v;
    }
    int lcn = lc[node], rcn = rc[node];
    float clv = cb[(size_t)lcn * HDIM + j];
    float crv = cb[(size_t)rcn * HDIM + j];
    float i_ = sigm(g[0]), o_ = sigm(g[1]), fl_ = sigm(g[2]), fr_ = sigm(g[3]);
    float u_ = tanhf(g[4]), r_ = sigm(g[5]);
    float c  = i_ * u_ + fl_ * clv + fr_ * crv;
    float hc = o_ * tanhf(c);
    float px = (float)pxr[j];
    float hf = r_ * hc + (1.0f - r_) * px;
    cb[(size_t)node * HDIM + j] = c;
    H[(size_t)node * 1024 + j] = (f16)hf;
    if (out32) out32[(size_t)node * 1024 + j] = hf;
}

__global__ __launch_bounds__(256) void elem_bwd(
    const f16* __restrict__ G,
    const f16* __restrict__ PX,
    int base, int m, const int* __restrict__ par,
    float* __restrict__ cb, f16* __restrict__ H, float* __restrict__ out32,
    const float* __restrict__ bh)
{
    int t = blockIdx.x * 256 + threadIdx.x;
    if (t >= m * HDIM) return;
    int row = t >> 9, j = t & (HDIM - 1);
    int node = base + row;
    const f16* pxr = PX + (size_t)node * NCAT;
    float g[5];
#pragma unroll
    for (int q = 0; q < 5; ++q)
        g[q] = (float)pxr[4096 + q * HDIM + j] + bh[q * HDIM + j]
             + (float)G[(size_t)row * 2560 + q * HDIM + j];
    int p = par[node];
    float cp = cb[(size_t)p * HDIM + j];
    float i_ = sigm(g[0]), o_ = sigm(g[1]), f_ = sigm(g[2]);
    float u_ = tanhf(g[3]), r_ = sigm(g[4]);
    float c  = i_ * u_ + f_ * cp;
    float hc = o_ * tanhf(c);
    float px = (float)pxr[3584 + j];
    float hf = r_ * hc + (1.0f - r_) * px;
    cb[(size_t)node * HDIM + j] = c;
    H[(size_t)node * 1024 + HDIM + j] = (f16)hf;
    if (out32) out32[(size_t)node * 1024 + HDIM + j] = hf;
}

extern "C" void kernel_launch(void* const* d_in, const int* in_sizes, int n_in,
                              void* d_out, int out_size, void* d_ws, size_t ws_size,
                              hipStream_t stream)
{
    (void)in_sizes; (void)n_in; (void)out_size; (void)ws_size;
    const float* features = (const float*)d_in[0];
    const float* fw_Wp = (const float*)d_in[1];
    const float* fw_bp = (const float*)d_in[2];
    const float* fw_Wx = (const float*)d_in[3];
    const float* fw_bx = (const float*)d_in[4];
    const float* fw_Wl = (const float*)d_in[5];
    const float* fw_bl = (const float*)d_in[6];
    const float* fw_Wr = (const float*)d_in[7];
    const float* fw_br = (const float*)d_in[8];
    const float* bw_Wp = (const float*)d_in[9];
    const float* bw_bp = (const float*)d_in[10];
    const float* bw_Wx = (const float*)d_in[11];
    const float* bw_bx = (const float*)d_in[12];
    const float* bw_Wh = (const float*)d_in[13];
    const float* bw_bh = (const float*)d_in[14];
    const int* lc  = (const int*)d_in[17];
    const int* rc  = (const int*)d_in[18];
    const int* par = (const int*)d_in[19];

    // workspace layout (f16 units unless noted), total ~112 MB
    f16* featb = (f16*)d_ws;
    f16* H     = featb + (size_t)4096 * 1024;
    f16* Wcat  = H     + (size_t)4097 * 1024;
    f16* Wlr   = Wcat  + (size_t)NCAT * 1024;
    f16* Wh    = Wlr   + (size_t)3072 * 1024;
    f16* PX    = Wh    + (size_t)2560 * 512;
    f16* G     = PX    + (size_t)4096 * NCAT;
    float* biascat = (float*)(G + (size_t)2048 * 3072);
    float* cb      = biascat + NCAT;

    zero_slots<<<dim3(1), dim3(1024), 0, stream>>>(H, cb);
    cvt16<<<dim3(2048), 256, 0, stream>>>(features, featb, 4096 * 1024 / 8);

    for (int l = 0; l < 2; ++l) {
        // per-layer weight conversion (stream-ordered; buffers reused)
        cvt16<<<dim3(256),  256, 0, stream>>>(fw_Wp + (size_t)l * 512 * 1024,  Wcat,               512 * 1024 / 8);
        cvt16<<<dim3(1536), 256, 0, stream>>>(fw_Wx + (size_t)l * 3072 * 1024, Wcat + 512 * 1024,  3072 * 1024 / 8);
        cvt16<<<dim3(256),  256, 0, stream>>>(bw_Wp + (size_t)l * 512 * 1024,  Wcat + 3584 * 1024, 512 * 1024 / 8);
        cvt16<<<dim3(1280), 256, 0, stream>>>(bw_Wx + (size_t)l * 2560 * 1024, Wcat + (size_t)4096 * 1024, 2560 * 1024 / 8);
        cvt16_lr<<<dim3(1536), 256, 0, stream>>>(fw_Wl + (size_t)l * 3072 * 512,
                                                 fw_Wr + (size_t)l * 3072 * 512, Wlr);
        cvt16<<<dim3(640), 256, 0, stream>>>(bw_Wh + (size_t)l * 2560 * 512, Wh, 2560 * 512 / 8);
        biascat_k<<<dim3(26), 256, 0, stream>>>(fw_bp + (size_t)l * 512, fw_bx + (size_t)l * 3072,
                                                bw_bp + (size_t)l * 512, bw_bx + (size_t)l * 2560, biascat);

        // fused precompute: PX[4096][6656] = A @ [Wp_f|Wx_f|Wp_b|Wx_b]^T + bias
        const f16* A16 = (l == 0) ? featb : H;
        mm16<0><<<dim3(NCAT / 128, 4096 / 128), 256, 0, stream>>>(
            A16, nullptr, nullptr, 0, 4096, Wcat, biascat, PX, NCAT, 1024);

        float* o32 = (l == 1) ? (float*)d_out : nullptr;
        const float* bl_l = fw_bl + (size_t)l * 3072;
        const float* br_l = fw_br + (size_t)l * 3072;

        // fwd leaves 2048..4095: children = zero slot, g = x2 + biases
        elem_fwd<<<dim3(2048 * 512 / 256), 256, 0, stream>>>(
            nullptr, 0, PX, 2048, 2048, lc, rc, cb, H, o32, bl_l, br_l);
        auto stageF = [&](int b, int m_) {
            mm16<1><<<dim3(3072 / 128, (m_ + 127) / 128), 256, 0, stream>>>(
                H, lc, rc, b, m_, Wlr, nullptr, G, 3072, 1024);
            elem_fwd<<<dim3((m_ * 512 + 255) / 256), 256, 0, stream>>>(
                G, 3072, PX, b, m_, lc, rc, cb, H, o32, bl_l, br_l);
        };
        stageF(2047, 1);                                    // needs leaf 4095
        for (int k = 10; k >= 0; --k) stageF((1 << k) - 1, 1 << k);

        const float* bh_l = bw_bh + (size_t)l * 2560;
        for (int k = 0; k <= 12; ++k) {
            int b  = (1 << k) - 1;
            int m_ = (1 << k); if (b + m_ > 4096) m_ = 4096 - b;
            mm16<2><<<dim3(2560 / 128, (m_ + 127) / 128), 256, 0, stream>>>(
                H, par, nullptr, b, m_, Wh, nullptr, G, 2560, 512);
            elem_bwd<<<dim3((m_ * 512 + 255) / 256), 256, 0, stream>>>(
                G, PX, b, m_, par, cb, H, o32, bh_l);
        }
    }
    // layer-2 elems wrote d_out directly; nothing else to copy
}

// Round 6
// 1408.748 us; speedup vs baseline: 2.8319x; 1.3187x over previous
//
#include <hip/hip_runtime.h>
#include <cstdint>
#include <cstddef>

// ---------------------------------------------------------------------------
// MultiLayer bidirectional TreeLSTM, N=4096 heap tree, H=512, L=2.
// R6: chain-shortening. fwd and bwd scans are independent within a layer
// (disjoint H halves, separate cell buffers) -> merge fwd stage i + bwd
// stage i into ONE GEMM launch (mmstage, 1D grid block-decode) and ONE
// elementwise launch (elem_merged). bwd root (parent = zero slot) needs no
// GEMM -> folded into the leaves elem. ~120 -> ~68 launches per call.
// cb split into cbf/cbb (required: scans now interleave).
// Gf aliases the feat16 region (feat16 dead after layer-0 precompute).
// GEMM core identical to R5 (f16 MFMA, fp32 acc). Workspace ~121 MB.
// ---------------------------------------------------------------------------

#define HDIM 512
#define ZROW 4096
#define NCAT 6656   // 512 px_f | 3072 x2_f | 512 px_b | 2560 x2_b

typedef _Float16 f16;
typedef f16   f16x8 __attribute__((ext_vector_type(8)));
typedef float f32x4 __attribute__((ext_vector_type(4)));

__device__ __forceinline__ float sigm(float x) { return 1.0f / (1.0f + expf(-x)); }

__global__ __launch_bounds__(256) void cvt16(
    const float* __restrict__ s, f16* __restrict__ d, int n8)
{
    int i = blockIdx.x * 256 + threadIdx.x;
    if (i >= n8) return;
    float4 v0 = ((const float4*)s)[(size_t)i * 2];
    float4 v1 = ((const float4*)s)[(size_t)i * 2 + 1];
    f16x8 o;
    o[0] = (f16)v0.x; o[1] = (f16)v0.y; o[2] = (f16)v0.z; o[3] = (f16)v0.w;
    o[4] = (f16)v1.x; o[5] = (f16)v1.y; o[6] = (f16)v1.z; o[7] = (f16)v1.w;
    *(f16x8*)(d + (size_t)i * 8) = o;
}

// concat Wl|Wr along K: dst[3072][1024] f16
__global__ __launch_bounds__(256) void cvt16_lr(
    const float* __restrict__ Wl, const float* __restrict__ Wr, f16* __restrict__ d)
{
    int i = blockIdx.x * 256 + threadIdx.x;   // over 3072*1024/8
    int col8 = (i * 8) & 1023;
    int row  = (i * 8) >> 10;
    const float* s = (col8 < HDIM) ? (Wl + (size_t)row * HDIM + col8)
                                   : (Wr + (size_t)row * HDIM + col8 - HDIM);
    float4 v0 = ((const float4*)s)[0];
    float4 v1 = ((const float4*)s)[1];
    f16x8 o;
    o[0] = (f16)v0.x; o[1] = (f16)v0.y; o[2] = (f16)v0.z; o[3] = (f16)v0.w;
    o[4] = (f16)v1.x; o[5] = (f16)v1.y; o[6] = (f16)v1.z; o[7] = (f16)v1.w;
    *(f16x8*)(d + (size_t)i * 8) = o;
}

__global__ __launch_bounds__(256) void biascat_k(
    const float* __restrict__ a, const float* __restrict__ b,
    const float* __restrict__ c, const float* __restrict__ dd,
    float* __restrict__ o)
{
    int t = blockIdx.x * 256 + threadIdx.x;
    if (t >= NCAT) return;
    float v;
    if (t < 512) v = a[t];
    else if (t < 3584) v = b[t - 512];
    else if (t < 4096) v = c[t - 3584];
    else v = dd[t - 4096];
    o[t] = v;
}

__global__ void zero_slots(f16* H, float* cbf, float* cbb)
{
    int t = threadIdx.x;  // 1024 threads
    H[(size_t)ZROW * 1024 + t] = (f16)0.0f;
    if (t < HDIM) {
        cbf[(size_t)ZROW * HDIM + t] = 0.0f;
        cbb[(size_t)ZROW * HDIM + t] = 0.0f;
    }
}

// ---------------------------------------------------------------------------
// Precompute GEMM: C[M,N] = A[M,K] @ W[N,K]^T + bias, f16 in, f32 acc, f16 out.
// 128x128 tile, 4 waves (2x2), each wave 4x4 MFMA 16x16x32 tiles.
// LDS row stride 40 f16 (80 B): 2-way bank aliasing only (free, m136).
// ---------------------------------------------------------------------------
__global__ __launch_bounds__(256) void mm_pre(
    const f16* __restrict__ A, const f16* __restrict__ W,
    const float* __restrict__ bias, f16* __restrict__ C, int N, int K)
{
    __shared__ __align__(16) f16 Al[128 * 40];
    __shared__ __align__(16) f16 Bl[128 * 40];
    const int t  = threadIdx.x;
    const int L  = t & 63;
    const int w  = t >> 6;
    const int wm = (w & 1) << 6;
    const int wn = (w >> 1) << 6;
    const int srow = t & 127;
    const int sch  = t >> 7;
    const int fr = L & 15;
    const int fq = L >> 4;

    const f16* ap = A + (size_t)(blockIdx.y * 128 + srow) * K;
    const f16* bp = W + (size_t)(blockIdx.x * 128 + srow) * K;

    f32x4 acc[4][4] = {};
    for (int k0 = 0; k0 < K; k0 += 32) {
        const int kc = k0 + sch * 16;
        f16x8 a0 = *(const f16x8*)(ap + kc);
        f16x8 a1 = *(const f16x8*)(ap + kc + 8);
        f16x8 b0 = *(const f16x8*)(bp + kc);
        f16x8 b1 = *(const f16x8*)(bp + kc + 8);
        __syncthreads();
        f16* ad = Al + srow * 40 + sch * 16;
        *(f16x8*)ad = a0; *(f16x8*)(ad + 8) = a1;
        f16* bd = Bl + srow * 40 + sch * 16;
        *(f16x8*)bd = b0; *(f16x8*)(bd + 8) = b1;
        __syncthreads();
        f16x8 af[4], bg[4];
#pragma unroll
        for (int i = 0; i < 4; ++i)
            af[i] = *(const f16x8*)(Al + (wm + i * 16 + fr) * 40 + fq * 8);
#pragma unroll
        for (int j = 0; j < 4; ++j)
            bg[j] = *(const f16x8*)(Bl + (wn + j * 16 + fr) * 40 + fq * 8);
#pragma unroll
        for (int i = 0; i < 4; ++i)
#pragma unroll
            for (int j = 0; j < 4; ++j)
                acc[i][j] = __builtin_amdgcn_mfma_f32_16x16x32_f16(
                    af[i], bg[j], acc[i][j], 0, 0, 0);
    }
    // C/D layout: col = lane&15, row = (lane>>4)*4 + reg  [m89-verified]
    const int gr0 = blockIdx.y * 128 + wm + fq * 4;
    const int gc0 = blockIdx.x * 128 + wn + fr;
#pragma unroll
    for (int j = 0; j < 4; ++j) {
        const int gc = gc0 + j * 16;
        const float bj = bias[gc];
#pragma unroll
        for (int i = 0; i < 4; ++i) {
            const int gr = gr0 + i * 16;
#pragma unroll
            for (int rr = 0; rr < 4; ++rr)
                C[(size_t)(gr + rr) * N + gc] = (f16)(acc[i][j][rr] + bj);
        }
    }
}

// ---------------------------------------------------------------------------
// Merged stage GEMM: one launch computes BOTH
//   fwd: Gf[r,0:3072] = H_f[lc]@Wl^T + H_f[rc]@Wr^T   (fm rows, K=1024)
//   bwd: Gb[r,0:2560] = H_b[par]@Wh^T                  (bm rows, K=512)
// 1D grid: first ceil(fm/128)*24 blocks are fwd tiles, rest bwd tiles.
// Gather index = base + GLOBAL row (R5 fix). Rows >= m use zero row.
// ---------------------------------------------------------------------------
__global__ __launch_bounds__(256) void mmstage(
    const f16* __restrict__ H,
    const int* __restrict__ lc, const int* __restrict__ rc,
    const int* __restrict__ par,
    int fbase, int fm, int bbase, int bm,
    const f16* __restrict__ Wlr, const f16* __restrict__ Wh,
    f16* __restrict__ Gf, f16* __restrict__ Gb)
{
    __shared__ __align__(16) f16 Al[128 * 40];
    __shared__ __align__(16) f16 Bl[128 * 40];
    const int t  = threadIdx.x;
    const int L  = t & 63;
    const int w  = t >> 6;
    const int wm = (w & 1) << 6;
    const int wn = (w >> 1) << 6;
    const int srow = t & 127;
    const int sch  = t >> 7;
    const int fr = L & 15;
    const int fq = L >> 4;

    const int nfB = ((fm + 127) >> 7) * 24;
    const int bid = blockIdx.x;
    const bool isF = bid < nfB;
    int by, bx, m, N, K;
    const f16* W;
    f16* C;
    if (isF) { by = bid / 24; bx = bid - by * 24; m = fm; N = 3072; K = 1024; W = Wlr; C = Gf; }
    else     { int b2 = bid - nfB; by = b2 / 20; bx = b2 - by * 20; m = bm; N = 2560; K = 512; W = Wh; C = Gb; }

    const int grow = by * 128 + srow;
    const f16* ap_lo;
    const f16* ap_hi;
    if (isF) {
        int n1 = ZROW, n2 = ZROW;
        if (grow < m) { n1 = lc[fbase + grow]; n2 = rc[fbase + grow]; }
        ap_lo = H + (size_t)n1 * 1024;          // fwd h of left child (k<512)
        ap_hi = H + (size_t)n2 * 1024;          // fwd h of right child (k>=512)
    } else {
        int n1 = ZROW;
        if (grow < m) n1 = par[bbase + grow];
        ap_lo = H + (size_t)n1 * 1024 + HDIM;   // bwd h of parent (K=512)
        ap_hi = ap_lo;                           // unused (K=512)
    }
    const f16* bp = W + (size_t)(bx * 128 + srow) * K;

    f32x4 acc[4][4] = {};
    for (int k0 = 0; k0 < K; k0 += 32) {
        const int kc = k0 + sch * 16;
        const f16* asrc = (kc < HDIM) ? (ap_lo + kc) : (ap_hi + (kc - HDIM));
        f16x8 a0 = *(const f16x8*)asrc;
        f16x8 a1 = *(const f16x8*)(asrc + 8);
        f16x8 b0 = *(const f16x8*)(bp + kc);
        f16x8 b1 = *(const f16x8*)(bp + kc + 8);
        __syncthreads();
        f16* ad = Al + srow * 40 + sch * 16;
        *(f16x8*)ad = a0; *(f16x8*)(ad + 8) = a1;
        f16* bd = Bl + srow * 40 + sch * 16;
        *(f16x8*)bd = b0; *(f16x8*)(bd + 8) = b1;
        __syncthreads();
        f16x8 af[4], bg[4];
#pragma unroll
        for (int i = 0; i < 4; ++i)
            af[i] = *(const f16x8*)(Al + (wm + i * 16 + fr) * 40 + fq * 8);
#pragma unroll
        for (int j = 0; j < 4; ++j)
            bg[j] = *(const f16x8*)(Bl + (wn + j * 16 + fr) * 40 + fq * 8);
#pragma unroll
        for (int i = 0; i < 4; ++i)
#pragma unroll
            for (int j = 0; j < 4; ++j)
                acc[i][j] = __builtin_amdgcn_mfma_f32_16x16x32_f16(
                    af[i], bg[j], acc[i][j], 0, 0, 0);
    }
    const int gr0 = by * 128 + wm + fq * 4;
    const int gc0 = bx * 128 + wn + fr;
#pragma unroll
    for (int j = 0; j < 4; ++j) {
        const int gc = gc0 + j * 16;
#pragma unroll
        for (int i = 0; i < 4; ++i) {
            const int gr = gr0 + i * 16;
#pragma unroll
            for (int rr = 0; rr < 4; ++rr) {
                if (gr + rr < m)
                    C[(size_t)(gr + rr) * N + gc] = (f16)acc[i][j][rr];
            }
        }
    }
}

// ---------------------------------------------------------------------------
// Merged elementwise: fwd cells for fm nodes at fbase (+Gf if non-null) and
// bwd cells for bm nodes at bbase (+Gb if non-null). Separate cbf/cbb.
// ---------------------------------------------------------------------------
__global__ __launch_bounds__(256) void elem_merged(
    const f16* __restrict__ Gf, const f16* __restrict__ Gb,
    const f16* __restrict__ PX,
    int fbase, int fm, int bbase, int bm,
    const int* __restrict__ lc, const int* __restrict__ rc,
    const int* __restrict__ par,
    float* __restrict__ cbf, float* __restrict__ cbb,
    f16* __restrict__ H, float* __restrict__ out32,
    const float* __restrict__ bl, const float* __restrict__ br,
    const float* __restrict__ bh)
{
    int t = blockIdx.x * 256 + threadIdx.x;
    const int ftot = fm * HDIM;
    if (t < ftot) {
        int row = t >> 9, j = t & (HDIM - 1);
        int node = fbase + row;
        const f16* pxr = PX + (size_t)node * NCAT;
        float g[6];
#pragma unroll
        for (int q = 0; q < 6; ++q) {
            float v = (float)pxr[HDIM + q * HDIM + j] + bl[q * HDIM + j] + br[q * HDIM + j];
            if (Gf) v += (float)Gf[(size_t)row * 3072 + q * HDIM + j];
            g[q] = v;
        }
        int lcn = lc[node], rcn = rc[node];
        float clv = cbf[(size_t)lcn * HDIM + j];
        float crv = cbf[(size_t)rcn * HDIM + j];
        float i_ = sigm(g[0]), o_ = sigm(g[1]), fl_ = sigm(g[2]), fr_ = sigm(g[3]);
        float u_ = tanhf(g[4]), r_ = sigm(g[5]);
        float c  = i_ * u_ + fl_ * clv + fr_ * crv;
        float hc = o_ * tanhf(c);
        float px = (float)pxr[j];
        float hf = r_ * hc + (1.0f - r_) * px;
        cbf[(size_t)node * HDIM + j] = c;
        H[(size_t)node * 1024 + j] = (f16)hf;
        if (out32) out32[(size_t)node * 1024 + j] = hf;
    } else {
        int t2 = t - ftot;
        if (t2 >= bm * HDIM) return;
        int row = t2 >> 9, j = t2 & (HDIM - 1);
        int node = bbase + row;
        const f16* pxr = PX + (size_t)node * NCAT;
        float g[5];
#pragma unroll
        for (int q = 0; q < 5; ++q) {
            float v = (float)pxr[4096 + q * HDIM + j] + bh[q * HDIM + j];
            if (Gb) v += (float)Gb[(size_t)row * 2560 + q * HDIM + j];
            g[q] = v;
        }
        int p = par[node];
        float cp = cbb[(size_t)p * HDIM + j];
        float i_ = sigm(g[0]), o_ = sigm(g[1]), f_ = sigm(g[2]);
        float u_ = tanhf(g[3]), r_ = sigm(g[4]);
        float c  = i_ * u_ + f_ * cp;
        float hc = o_ * tanhf(c);
        float px = (float)pxr[3584 + j];
        float hf = r_ * hc + (1.0f - r_) * px;
        cbb[(size_t)node * HDIM + j] = c;
        H[(size_t)node * 1024 + HDIM + j] = (f16)hf;
        if (out32) out32[(size_t)node * 1024 + HDIM + j] = hf;
    }
}

extern "C" void kernel_launch(void* const* d_in, const int* in_sizes, int n_in,
                              void* d_out, int out_size, void* d_ws, size_t ws_size,
                              hipStream_t stream)
{
    (void)in_sizes; (void)n_in; (void)out_size; (void)ws_size;
    const float* features = (const float*)d_in[0];
    const float* fw_Wp = (const float*)d_in[1];
    const float* fw_bp = (const float*)d_in[2];
    const float* fw_Wx = (const float*)d_in[3];
    const float* fw_bx = (const float*)d_in[4];
    const float* fw_Wl = (const float*)d_in[5];
    const float* fw_bl = (const float*)d_in[6];
    const float* fw_Wr = (const float*)d_in[7];
    const float* fw_br = (const float*)d_in[8];
    const float* bw_Wp = (const float*)d_in[9];
    const float* bw_bp = (const float*)d_in[10];
    const float* bw_Wx = (const float*)d_in[11];
    const float* bw_bx = (const float*)d_in[12];
    const float* bw_Wh = (const float*)d_in[13];
    const float* bw_bh = (const float*)d_in[14];
    const int* lc  = (const int*)d_in[17];
    const int* rc  = (const int*)d_in[18];
    const int* par = (const int*)d_in[19];

    // workspace layout (f16 units unless noted), ~121 MB.
    // Gf ALIASES feat16: feat16 is only read by the layer-0 precompute, which
    // completes (stream order) before the first mmstage writes Gf.
    f16* feat16 = (f16*)d_ws;                       // 4096*1024
    f16* Gf     = feat16;                           // 1024*3072 <= 4096*1024
    f16* H      = feat16 + (size_t)4096 * 1024;     // 4097*1024
    f16* Wcat   = H     + (size_t)4097 * 1024;      // 6656*1024
    f16* Wlr    = Wcat  + (size_t)NCAT * 1024;      // 3072*1024
    f16* Wh     = Wlr   + (size_t)3072 * 1024;      // 2560*512
    f16* PX     = Wh    + (size_t)2560 * 512;       // 4096*6656
    f16* Gb     = PX    + (size_t)4096 * NCAT;      // 2048*2560
    float* biascat = (float*)(Gb + (size_t)2048 * 2560);
    float* cbf     = biascat + NCAT;                // 4097*512 f32
    float* cbb     = cbf + (size_t)4097 * HDIM;     // 4097*512 f32

    zero_slots<<<dim3(1), dim3(1024), 0, stream>>>(H, cbf, cbb);
    cvt16<<<dim3(2048), 256, 0, stream>>>(features, feat16, 4096 * 1024 / 8);

    // stage schedule (per layer): merged launch i pairs fwd stage i with bwd
    // stage i. fwd: special node 2047, then levels 10..0. bwd: levels 1..12.
    static const int fb[12] = {2047, 1023, 511, 255, 127, 63, 31, 15, 7, 3, 1, 0};
    static const int fmv[12] = {1, 1024, 512, 256, 128, 64, 32, 16, 8, 4, 2, 1};
    static const int bb[12] = {1, 3, 7, 15, 31, 63, 127, 255, 511, 1023, 2047, 4095};
    static const int bmv[12] = {2, 4, 8, 16, 32, 64, 128, 256, 512, 1024, 2048, 1};

    for (int l = 0; l < 2; ++l) {
        cvt16<<<dim3(256),  256, 0, stream>>>(fw_Wp + (size_t)l * 512 * 1024,  Wcat,               512 * 1024 / 8);
        cvt16<<<dim3(1536), 256, 0, stream>>>(fw_Wx + (size_t)l * 3072 * 1024, Wcat + 512 * 1024,  3072 * 1024 / 8);
        cvt16<<<dim3(256),  256, 0, stream>>>(bw_Wp + (size_t)l * 512 * 1024,  Wcat + 3584 * 1024, 512 * 1024 / 8);
        cvt16<<<dim3(1280), 256, 0, stream>>>(bw_Wx + (size_t)l * 2560 * 1024, Wcat + (size_t)4096 * 1024, 2560 * 1024 / 8);
        cvt16_lr<<<dim3(1536), 256, 0, stream>>>(fw_Wl + (size_t)l * 3072 * 512,
                                                 fw_Wr + (size_t)l * 3072 * 512, Wlr);
        cvt16<<<dim3(640), 256, 0, stream>>>(bw_Wh + (size_t)l * 2560 * 512, Wh, 2560 * 512 / 8);
        biascat_k<<<dim3(26), 256, 0, stream>>>(fw_bp + (size_t)l * 512, fw_bx + (size_t)l * 3072,
                                                bw_bp + (size_t)l * 512, bw_bx + (size_t)l * 2560, biascat);

        // fused precompute: PX[4096][6656] = A @ [Wp_f|Wx_f|Wp_b|Wx_b]^T + bias
        const f16* A16 = (l == 0) ? feat16 : H;
        mm_pre<<<dim3(NCAT / 128, 4096 / 128), 256, 0, stream>>>(
            A16, Wcat, biascat, PX, NCAT, 1024);

        float* o32 = (l == 1) ? (float*)d_out : nullptr;
        const float* bl_l = fw_bl + (size_t)l * 3072;
        const float* br_l = fw_br + (size_t)l * 3072;
        const float* bh_l = bw_bh + (size_t)l * 2560;

        // merged leaves (fwd, m=2048) + root (bwd, m=1): no GEMM needed
        {
            int tot = (2048 + 1) * HDIM;
            elem_merged<<<dim3((tot + 255) / 256), 256, 0, stream>>>(
                nullptr, nullptr, PX, 2048, 2048, 0, 1,
                lc, rc, par, cbf, cbb, H, o32, bl_l, br_l, bh_l);
        }
        for (int i = 0; i < 12; ++i) {
            int nfB = ((fmv[i] + 127) >> 7) * 24;
            int nbB = ((bmv[i] + 127) >> 7) * 20;
            mmstage<<<dim3(nfB + nbB), 256, 0, stream>>>(
                H, lc, rc, par, fb[i], fmv[i], bb[i], bmv[i], Wlr, Wh, Gf, Gb);
            int tot = (fmv[i] + bmv[i]) * HDIM;
            elem_merged<<<dim3((tot + 255) / 256), 256, 0, stream>>>(
                Gf, Gb, PX, fb[i], fmv[i], bb[i], bmv[i],
                lc, rc, par, cbf, cbb, H, o32, bl_l, br_l, bh_l);
        }
    }
    // layer-1 elems wrote d_out directly; nothing else to copy
}